// Round 8
// baseline (373.033 us; speedup 1.0000x reference)
//
#include <hip/hip_runtime.h>
#include <stdint.h>

#define NN   2048
#define DD   128
#define DIN  256
#define ROWZ 75

typedef float f32x4 __attribute__((ext_vector_type(4)));
typedef short bf16x8 __attribute__((ext_vector_type(8)));
typedef unsigned int u32x4 __attribute__((ext_vector_type(4)));
typedef unsigned int u32x2 __attribute__((ext_vector_type(2)));

__device__ __forceinline__ unsigned short f2bf(float x){
  union { float f; unsigned int u; } v; v.f = x;
  unsigned int u = v.u;
  u += 0x7fffu + ((u >> 16) & 1u);   // RNE
  return (unsigned short)(u >> 16);
}
__device__ __forceinline__ float bf2f(unsigned short b){
  union { float f; unsigned int u; } v; v.u = ((unsigned int)b) << 16;
  return v.f;
}

// ---------------------------------------------------------------------------
// Kernel A: Wh = h @ W (fp32), row L2 norms.  (unchanged — passed 4x)
// ---------------------------------------------------------------------------
__launch_bounds__(256, 2)
__global__ void wh_kernel(const float* __restrict__ h, const float* __restrict__ W,
                          unsigned short* __restrict__ whn, unsigned short* __restrict__ whT)
{
  __shared__ float hs[32][36];
  __shared__ float Ws[32][128];
  __shared__ float ssp[32][33];
  __shared__ float sinv[32];

  const int t  = threadIdx.x;
  const int r0 = blockIdx.x * 32;
  const int r4 = (t >> 5) * 4;
  const int d4 = (t & 31) * 4;

  float acc[4][4];
#pragma unroll
  for (int i = 0; i < 4; ++i)
#pragma unroll
    for (int j = 0; j < 4; ++j) acc[i][j] = 0.f;

  const int lrow = t >> 3;
  const int lkb  = (t & 7) * 4;

  for (int kt = 0; kt < 8; ++kt){
    __syncthreads();
    {
      const float* src = h + (size_t)(r0 + lrow) * DIN + kt * 32 + lkb;
      f32x4 a = *(const f32x4*)src;
#pragma unroll
      for (int e = 0; e < 4; ++e) hs[lkb + e][lrow] = a[e];
    }
    {
      const int k = t >> 3;
      const int d = (t & 7) * 16;
      const float* src = W + (size_t)(kt * 32 + k) * DD + d;
      float* dst = &Ws[k][d];
#pragma unroll
      for (int e = 0; e < 4; ++e) ((f32x4*)dst)[e] = ((const f32x4*)src)[e];
    }
    __syncthreads();
#pragma unroll
    for (int k = 0; k < 32; ++k){
      f32x4 w4 = *(const f32x4*)&Ws[k][d4];
      f32x4 ha = *(const f32x4*)&hs[k][r4];
#pragma unroll
      for (int i = 0; i < 4; ++i)
#pragma unroll
        for (int j = 0; j < 4; ++j)
          acc[i][j] += ha[i] * w4[j];
    }
  }

#pragma unroll
  for (int i = 0; i < 4; ++i){
    float s = acc[i][0]*acc[i][0] + acc[i][1]*acc[i][1]
            + acc[i][2]*acc[i][2] + acc[i][3]*acc[i][3];
    ssp[r4 + i][t & 31] = s;
  }
  __syncthreads();
  if (t < 32){
    float ss = 0.f;
#pragma unroll
    for (int c = 0; c < 32; ++c) ss += ssp[t][c];
    sinv[t] = 1.0f / fmaxf(sqrtf(ss), 1e-12f);
  }
  __syncthreads();

  const int bb = r0 >> 11;
  const int n0 = (r0 & 2047) + r4;

#pragma unroll
  for (int i = 0; i < 4; ++i){
    const float inv = sinv[r4 + i];
    unsigned int lo = (unsigned int)f2bf(acc[i][0]*inv) | ((unsigned int)f2bf(acc[i][1]*inv) << 16);
    unsigned int hi = (unsigned int)f2bf(acc[i][2]*inv) | ((unsigned int)f2bf(acc[i][3]*inv) << 16);
    u32x2 pk = { lo, hi };
    *(u32x2*)(whn + (size_t)(r0 + r4 + i) * DD + d4) = pk;
  }
#pragma unroll
  for (int j = 0; j < 4; ++j){
    u32x2 pk;
#pragma unroll
    for (int e = 0; e < 2; ++e)
      pk[e] = (unsigned int)f2bf(acc[2*e][j]) | ((unsigned int)f2bf(acc[2*e + 1][j]) << 16);
    *(u32x2*)(whT + ((size_t)(bb * DD + d4 + j)) * NN + n0) = pk;
  }
}

// ---------------------------------------------------------------------------
// Kernel B (R8): WAVE-AUTONOMOUS fused attention — no per-iteration barriers.
// R7 A/B proved the 2-barrier/iter structure (not adj traffic) costs ~82 µs:
// each barrier drains vmcnt(0) for all waves collectively. Here: block = 2
// waves over the SAME 16 q-rows; wave w sweeps m in [w*1024, w*1024+1024)
// independently (32 iters x 32 m). P round-trips wave-private LDS (lgkmcnt
// only). adj read inline, issued AFTER kf/vf so FIFO vmcnt lets QK run on kf
// while adj is in flight; exp computed before the adj select. One barrier
// total (final cross-wave O/l reduce). 12 waves/CU via __launch_bounds__.
// b = blockIdx&7 pins each batch's 1 MB whn/whT slice to one XCD's L2.
// ---------------------------------------------------------------------------
__launch_bounds__(128, 3)
__global__ void attn_kernel(const unsigned short* __restrict__ whn,
                            const unsigned short* __restrict__ whT,
                            const int* __restrict__ adj,
                            float* __restrict__ out)
{
  __shared__ unsigned short Pbuf[2][16 * 40];   // 2.5 KB: per-wave P
  __shared__ float Ored[16 * 132];              // 8.25 KB: cross-wave O reduce
  __shared__ float Lred[16];

  const int t    = threadIdx.x;
  const int w    = t >> 6;
  const int l    = t & 63;
  const int quad = l >> 4;
  const int l16  = l & 15;
  const int b    = blockIdx.x & 7;              // batch -> XCD pin
  const int qt   = blockIdx.x >> 3;             // 0..127
  const int q0   = qt * 16;

  const unsigned short* whn_b = whn + (size_t)b * NN * DD;
  const unsigned short* whT_b = whT + (size_t)b * DD * NN;
  const int*            adj_b = adj + (size_t)b * NN * NN;

  // persistent Q fragments (A-layout: row=l16, k=quad*8+j)
  bf16x8 qf[4];
#pragma unroll
  for (int kc = 0; kc < 4; ++kc)
    qf[kc] = *(const bf16x8*)(whn_b + (size_t)(q0 + l16) * DD + kc*32 + quad*8);

  f32x4 oacc[8];
  float lacc[4];
#pragma unroll
  for (int dt = 0; dt < 8; ++dt) oacc[dt] = (f32x4){0.f, 0.f, 0.f, 0.f};
#pragma unroll
  for (int r = 0; r < 4; ++r) lacc[r] = 0.f;

  unsigned short* const Pw = &Pbuf[w][0];
  const int arow = q0 + quad*4;                 // +r = this lane's q rows

  const int mbase = w * 1024;                   // wave's m half
  for (int it = 0; it < 32; ++it){
    const int m0 = mbase + it * 32;

    // ---- batched loads: kf, vf first (L2), adj LAST (HBM; FIFO lets QK
    //      consume kf/vf without draining adj) ----
    bf16x8 kf[2][4], vf[8];
    int av[2][4];
#pragma unroll
    for (int f = 0; f < 2; ++f)
#pragma unroll
      for (int kc = 0; kc < 4; ++kc)
        kf[f][kc] = *(const bf16x8*)(whn_b + (size_t)(m0 + f*16 + l16) * DD + kc*32 + quad*8);
#pragma unroll
    for (int dt = 0; dt < 8; ++dt)
      vf[dt] = *(const bf16x8*)(whT_b + (size_t)(dt*16 + l16) * NN + m0 + quad*8);
#pragma unroll
    for (int f = 0; f < 2; ++f)
#pragma unroll
      for (int r = 0; r < 4; ++r)
        av[f][r] = adj_b[(size_t)(arow + r) * NN + m0 + f*16 + l16];

    // ---- QK (waits kf only) + exp (no adj dep) + adj select -> P ----
#pragma unroll
    for (int f = 0; f < 2; ++f){
      f32x4 sc = (f32x4){0.f, 0.f, 0.f, 0.f};
#pragma unroll
      for (int kc = 0; kc < 4; ++kc)
        sc = __builtin_amdgcn_mfma_f32_16x16x32_bf16(qf[kc], kf[f][kc], sc, 0, 0, 0);
#pragma unroll
      for (int r = 0; r < 4; ++r){
        const int qrow = arow + r;
        float sv  = (qrow < ROWZ) ? 0.f : sc[r];            // row-zeroing bug emulation
        float e   = __expf(sv);                             // before adj wait
        float p32 = (av[f][r] > 0) ? e : 0.f;
        unsigned short pb = f2bf(p32);
        lacc[r] += bf2f(pb);
        Pw[(quad*4 + r) * 40 + f*16 + l16] = pb;            // C-layout -> LDS
      }
    }

    // ---- PV: O += P[16x32] * V[32x128] (wave-local P) ----
    {
      bf16x8 pf = *(const bf16x8*)&Pw[l16 * 40 + quad*8];   // A-layout read
#pragma unroll
      for (int dt = 0; dt < 8; ++dt)
        oacc[dt] = __builtin_amdgcn_mfma_f32_16x16x32_bf16(pf, vf[dt], oacc[dt], 0, 0, 0);
    }
  }

  // ---- in-wave l reduction over the 16 cols (lanes sharing a quad) ----
  float lsum[4];
#pragma unroll
  for (int r = 0; r < 4; ++r){
    float s = lacc[r];
    s += __shfl_xor(s, 1);
    s += __shfl_xor(s, 2);
    s += __shfl_xor(s, 4);
    s += __shfl_xor(s, 8);
    lsum[r] = s;                                // partial over this wave's m half
  }

  // ---- cross-wave reduce (the kernel's ONLY barrier) ----
  if (w == 1){
#pragma unroll
    for (int dt = 0; dt < 8; ++dt)
#pragma unroll
      for (int r = 0; r < 4; ++r)
        Ored[(quad*4 + r) * 132 + dt*16 + l16] = oacc[dt][r];
    if (l16 == 0){
#pragma unroll
      for (int r = 0; r < 4; ++r) Lred[quad*4 + r] = lsum[r];
    }
  }
  __syncthreads();
  if (w == 0){
    float linv[4];
#pragma unroll
    for (int r = 0; r < 4; ++r)
      linv[r] = 1.0f / (lsum[r] + Lred[quad*4 + r]);
#pragma unroll
    for (int dt = 0; dt < 8; ++dt)
#pragma unroll
      for (int r = 0; r < 4; ++r){
        float v = (oacc[dt][r] + Ored[(quad*4 + r) * 132 + dt*16 + l16]) * linv[r];
        v = (v > 0.f) ? v : expm1f(v);          // ELU (alpha=1)
        out[((size_t)b * NN + q0 + quad*4 + r) * DD + dt*16 + l16] = v;
      }
  }
}

extern "C" void kernel_launch(void* const* d_in, const int* in_sizes, int n_in,
                              void* d_out, int out_size, void* d_ws, size_t ws_size,
                              hipStream_t stream)
{
  const float* h       = (const float*)d_in[0];
  // d_in[1] = adj (unused by the reference; not touched)
  const int*   adj_eye = (const int*)d_in[2];
  const float* W       = (const float*)d_in[3];
  float*       out     = (float*)d_out;

  unsigned short* whn  = (unsigned short*)d_ws;                   // 4 MB
  unsigned short* whT  = whn + (size_t)16384 * 128;               // 4 MB (ws total 8 MB, proven)

  wh_kernel<<<512, 256, 0, stream>>>(h, W, whn, whT);
  attn_kernel<<<1024, 128, 0, stream>>>(whn, whT, adj_eye, out);
}